// Round 1
// baseline (208.091 us; speedup 1.0000x reference)
//
#include <hip/hip_runtime.h>
#include <math.h>

// Problem constants (from reference)
#define NROWS 84
#define SLEN  131072
#define BLOCKS_PER_ROW 32
#define THREADS 256
// Elements per block = SLEN / BLOCKS_PER_ROW = 4096 floats = 1024 float4
// Per thread: 4096 / 256 = 16 floats = 4 float4 loads from each tensor.

__global__ __launch_bounds__(THREADS) void rowdot_kernel(
    const float* __restrict__ ST0, const float* __restrict__ W0,
    const float* __restrict__ ST1, const float* __restrict__ W1,
    const float* __restrict__ BEV, const float* __restrict__ BEV_p,
    const float* __restrict__ B, float* __restrict__ tmp /* 168 floats */)
{
    const int bid = blockIdx.x;
    const int tensor = (bid >= NROWS * BLOCKS_PER_ROW) ? 1 : 0;
    const int local  = bid - tensor * NROWS * BLOCKS_PER_ROW;
    const int row = local / BLOCKS_PER_ROW;
    const int seg = local % BLOCKS_PER_ROW;

    const float* __restrict__ STp = tensor ? ST1 : ST0;
    const float* __restrict__ Wp  = tensor ? W1  : W0;

    const float bias = fmaxf(BEV_p[0], 0.0f) * BEV[0];
    const float b    = B[0];

    const size_t base = (size_t)row * SLEN + (size_t)seg * (SLEN / BLOCKS_PER_ROW);
    const float4* __restrict__ st4 = (const float4*)(STp + base);
    const float4* __restrict__ w4  = (const float4*)(Wp + base);

    const int t = threadIdx.x;
    float acc = 0.0f;

#pragma unroll
    for (int i = 0; i < 4; ++i) {
        float4 s = st4[t + i * THREADS];
        float4 w = w4[t + i * THREADS];
        // sigmoid(b*(bias+x)) = 1/(1+exp(-b*(bias+x)))
        acc += w.x * __frcp_rn(1.0f + __expf(-b * (bias + s.x)));
        acc += w.y * __frcp_rn(1.0f + __expf(-b * (bias + s.y)));
        acc += w.z * __frcp_rn(1.0f + __expf(-b * (bias + s.z)));
        acc += w.w * __frcp_rn(1.0f + __expf(-b * (bias + s.w)));
    }

    // wave-64 reduction
#pragma unroll
    for (int off = 32; off > 0; off >>= 1)
        acc += __shfl_down(acc, off, 64);

    __shared__ float sdata[THREADS / 64];
    if ((t & 63) == 0) sdata[t >> 6] = acc;
    __syncthreads();

    if (t == 0) {
        float s = 0.0f;
#pragma unroll
        for (int w = 0; w < THREADS / 64; ++w) s += sdata[w];
        atomicAdd(&tmp[tensor * NROWS + row], s);
    }
}

__global__ void finalize_kernel(
    const float* __restrict__ tmp,
    const float* __restrict__ p0, const float* __restrict__ p1,
    const float* __restrict__ p2, const float* __restrict__ p3,
    const float* __restrict__ p4, float* __restrict__ out)
{
    if (threadIdx.x != 0 || blockIdx.x != 0) return;

    const float* logits[5] = {p0, p1, p2, p3, p4};
    float total = 0.0f;

    for (int set = 0; set < 5; ++set) {
        const float* lg = logits[set];
        // softmax over 4 logits
        float m = fmaxf(fmaxf(lg[0], lg[1]), fmaxf(lg[2], lg[3]));
        float e[4], sum = 0.0f;
        for (int i = 0; i < 4; ++i) { e[i] = expf(lg[i] - m); sum += e[i]; }
        float p[4];
        for (int i = 0; i < 4; ++i) p[i] = e[i] / sum;

        // tmp row: set 0 uses tmp0 (first 84), sets 1..4 use tmp1 (second 84)
        const float* tv = (set == 0) ? tmp : tmp + NROWS;

        // 84-entry nested-product order:
        // for i: [p_i, for j: [p_i*p_j, for k: p_i*p_j*p_k]]
        float dot = 0.0f;
        int idx = 0;
        for (int i = 0; i < 4; ++i) {
            dot += p[i] * tv[idx++];
            for (int j = 0; j < 4; ++j) {
                float pij = p[i] * p[j];
                dot += pij * tv[idx++];
                for (int k = 0; k < 4; ++k)
                    dot += pij * p[k] * tv[idx++];
            }
        }
        total += dot;
    }
    out[0] = total * 0.2f;  // mean of 5 vals
}

extern "C" void kernel_launch(void* const* d_in, const int* in_sizes, int n_in,
                              void* d_out, int out_size, void* d_ws, size_t ws_size,
                              hipStream_t stream) {
    // setup_inputs() order:
    // 0 BEV(1) 1 ST0(84*131072) 2 Weight0 3 ST1 4 Weight1
    // 5..9 probs0..4 (4 each) 10 BEV_p(1) 11 B(1)
    const float* BEV   = (const float*)d_in[0];
    const float* ST0   = (const float*)d_in[1];
    const float* W0    = (const float*)d_in[2];
    const float* ST1   = (const float*)d_in[3];
    const float* W1    = (const float*)d_in[4];
    const float* p0    = (const float*)d_in[5];
    const float* p1    = (const float*)d_in[6];
    const float* p2    = (const float*)d_in[7];
    const float* p3    = (const float*)d_in[8];
    const float* p4    = (const float*)d_in[9];
    const float* BEV_p = (const float*)d_in[10];
    const float* B     = (const float*)d_in[11];

    float* tmp = (float*)d_ws;                 // 168 floats of partial row-dots
    float* out = (float*)d_out;

    // d_ws is poisoned 0xAA before every launch — zero the accumulators.
    hipMemsetAsync(tmp, 0, 2 * NROWS * sizeof(float), stream);

    const int grid = 2 * NROWS * BLOCKS_PER_ROW;  // 5376 blocks
    rowdot_kernel<<<grid, THREADS, 0, stream>>>(ST0, W0, ST1, W1, BEV, BEV_p, B, tmp);
    finalize_kernel<<<1, 64, 0, stream>>>(tmp, p0, p1, p2, p3, p4, out);
}

// Round 2
// 207.539 us; speedup vs baseline: 1.0027x; 1.0027x over previous
//
#include <hip/hip_runtime.h>
#include <math.h>

// Problem constants (from reference)
#define NROWS 84
#define SLEN  131072
#define BLOCKS_PER_ROW 32
#define THREADS 256
// Elements per block = SLEN / BLOCKS_PER_ROW = 4096 floats = 1024 float4
// Per thread: 16 floats = 4 float4 loads from each tensor, all 8 issued
// back-to-back before first use (the R0 version serialized at VGPR=24).

__global__ __launch_bounds__(THREADS) void rowdot_kernel(
    const float* __restrict__ ST0, const float* __restrict__ W0,
    const float* __restrict__ ST1, const float* __restrict__ W1,
    const float* __restrict__ BEV, const float* __restrict__ BEV_p,
    const float* __restrict__ B, float* __restrict__ tmp /* 168 floats */)
{
    const int bid = blockIdx.x;
    const int tensor = (bid >= NROWS * BLOCKS_PER_ROW) ? 1 : 0;
    const int local  = bid - tensor * NROWS * BLOCKS_PER_ROW;
    const int row = local / BLOCKS_PER_ROW;
    const int seg = local % BLOCKS_PER_ROW;

    const float* __restrict__ STp = tensor ? ST1 : ST0;
    const float* __restrict__ Wp  = tensor ? W1  : W0;

    const float bias = fmaxf(BEV_p[0], 0.0f) * BEV[0];
    const float b    = B[0];

    const size_t base = (size_t)row * SLEN + (size_t)seg * (SLEN / BLOCKS_PER_ROW);
    const float4* __restrict__ st4 = (const float4*)(STp + base);
    const float4* __restrict__ w4  = (const float4*)(Wp + base);

    const int t = threadIdx.x;

    // Stage ALL loads first — 8 independent global_load_dwordx4 in flight
    // per lane (8 KB/wave) to cover HBM latency. Do not touch values until
    // every load is issued.
    float4 s[4], w[4];
#pragma unroll
    for (int i = 0; i < 4; ++i) s[i] = st4[t + i * THREADS];
#pragma unroll
    for (int i = 0; i < 4; ++i) w[i] = w4[t + i * THREADS];

    // 4 independent accumulator chains (exp/rcp latency hiding)
    float a0 = 0.f, a1 = 0.f, a2 = 0.f, a3 = 0.f;
#pragma unroll
    for (int i = 0; i < 4; ++i) {
        a0 += w[i].x * __frcp_rn(1.0f + __expf(-b * (bias + s[i].x)));
        a1 += w[i].y * __frcp_rn(1.0f + __expf(-b * (bias + s[i].y)));
        a2 += w[i].z * __frcp_rn(1.0f + __expf(-b * (bias + s[i].z)));
        a3 += w[i].w * __frcp_rn(1.0f + __expf(-b * (bias + s[i].w)));
    }
    float acc = (a0 + a1) + (a2 + a3);

    // wave-64 reduction
#pragma unroll
    for (int off = 32; off > 0; off >>= 1)
        acc += __shfl_down(acc, off, 64);

    __shared__ float sdata[THREADS / 64];
    const int lane = t & 63;
    if (lane == 0) sdata[t >> 6] = acc;
    __syncthreads();

    if (t == 0) {
        float ssum = 0.0f;
#pragma unroll
        for (int wv = 0; wv < THREADS / 64; ++wv) ssum += sdata[wv];
        atomicAdd(&tmp[tensor * NROWS + row], ssum);
    }
}

__global__ void finalize_kernel(
    const float* __restrict__ tmp,
    const float* __restrict__ p0, const float* __restrict__ p1,
    const float* __restrict__ p2, const float* __restrict__ p3,
    const float* __restrict__ p4, float* __restrict__ out)
{
    if (threadIdx.x != 0 || blockIdx.x != 0) return;

    const float* logits[5] = {p0, p1, p2, p3, p4};
    float total = 0.0f;

    for (int set = 0; set < 5; ++set) {
        const float* lg = logits[set];
        float m = fmaxf(fmaxf(lg[0], lg[1]), fmaxf(lg[2], lg[3]));
        float e[4], sum = 0.0f;
        for (int i = 0; i < 4; ++i) { e[i] = expf(lg[i] - m); sum += e[i]; }
        float p[4];
        for (int i = 0; i < 4; ++i) p[i] = e[i] / sum;

        const float* tv = (set == 0) ? tmp : tmp + NROWS;

        float dot = 0.0f;
        int idx = 0;
        for (int i = 0; i < 4; ++i) {
            dot += p[i] * tv[idx++];
            for (int j = 0; j < 4; ++j) {
                float pij = p[i] * p[j];
                dot += pij * tv[idx++];
                for (int k = 0; k < 4; ++k)
                    dot += pij * p[k] * tv[idx++];
            }
        }
        total += dot;
    }
    out[0] = total * 0.2f;  // mean of 5 vals
}

extern "C" void kernel_launch(void* const* d_in, const int* in_sizes, int n_in,
                              void* d_out, int out_size, void* d_ws, size_t ws_size,
                              hipStream_t stream) {
    const float* BEV   = (const float*)d_in[0];
    const float* ST0   = (const float*)d_in[1];
    const float* W0    = (const float*)d_in[2];
    const float* ST1   = (const float*)d_in[3];
    const float* W1    = (const float*)d_in[4];
    const float* p0    = (const float*)d_in[5];
    const float* p1    = (const float*)d_in[6];
    const float* p2    = (const float*)d_in[7];
    const float* p3    = (const float*)d_in[8];
    const float* p4    = (const float*)d_in[9];
    const float* BEV_p = (const float*)d_in[10];
    const float* B     = (const float*)d_in[11];

    float* tmp = (float*)d_ws;                 // 168 floats of partial row-dots
    float* out = (float*)d_out;

    hipMemsetAsync(tmp, 0, 2 * NROWS * sizeof(float), stream);

    const int grid = 2 * NROWS * BLOCKS_PER_ROW;  // 5376 blocks
    rowdot_kernel<<<grid, THREADS, 0, stream>>>(ST0, W0, ST1, W1, BEV, BEV_p, B, tmp);
    finalize_kernel<<<1, 64, 0, stream>>>(tmp, p0, p1, p2, p3, p4, out);
}